// Round 6
// baseline (776.349 us; speedup 1.0000x reference)
//
#include <hip/hip_runtime.h>
#include <stdint.h>

using u16 = unsigned short;
typedef __attribute__((ext_vector_type(8))) __bf16 bf16x8;
typedef __attribute__((ext_vector_type(4))) float f32x4;

#define DEV __device__ __forceinline__

static constexpr int kB = 4, kL = 4096, kD = 1024, kFF = 4096;
static constexpr int kM = kB * kL;
static constexpr int kLC = 256, kNC = kL / kLC;
static constexpr float kEPS = 1e-6f;

DEV u16 f2bf(float v) {
  union { float f; uint32_t u; } x; x.f = v;
  uint32_t r = x.u + 0x7FFFu + ((x.u >> 16) & 1u);  // RNE
  return (u16)(r >> 16);
}
DEV float bf2f(u16 u) {
  union { uint32_t u; float f; } x; x.u = (uint32_t)u << 16; return x.f;
}
DEV float sigm(float x) { return 1.0f / (1.0f + __expf(-x)); }

DEV void gload_lds16(const void* g, void* l) {
  __builtin_amdgcn_global_load_lds(
      (const __attribute__((address_space(1))) void*)g,
      (__attribute__((address_space(3))) void*)l, 16, 0, 0);
}

// ---------------- weight transpose + f32->bf16: out[n*K+k] = bf16(in[k*N+n])
__global__ __launch_bounds__(256) void wtrans_kernel(const float* __restrict__ in,
                                                     u16* __restrict__ out,
                                                     int K, int N) {
  __shared__ float t[32][33];
  const int n0 = blockIdx.x * 32, k0 = blockIdx.y * 32;
  const int tx = threadIdx.x, ty = threadIdx.y;
#pragma unroll
  for (int i = 0; i < 4; ++i)
    t[ty + i * 8][tx] = in[(size_t)(k0 + ty + i * 8) * N + (n0 + tx)];
  __syncthreads();
#pragma unroll
  for (int i = 0; i < 4; ++i)
    out[(size_t)(n0 + ty + i * 8) * K + (k0 + tx)] = f2bf(t[tx][ty + i * 8]);
}

// paired transpose: out rows interleave a and b in 32-col groups.
// out row n (of 2*Ncols): g=n>>6, r=n&63; src = (r<32? a : b), col = g*32 + (r&31).
__global__ __launch_bounds__(256) void wtrans_pair(const float* __restrict__ a,
                                                   const float* __restrict__ b,
                                                   u16* __restrict__ out,
                                                   int K, int Ncols) {
  __shared__ float t[32][33];
  const int n0 = blockIdx.x * 32, k0 = blockIdx.y * 32;
  const int sel = (n0 >> 5) & 1;
  const int c0 = (n0 >> 6) * 32;
  const float* __restrict__ src = sel ? b : a;
  const int tx = threadIdx.x, ty = threadIdx.y;
#pragma unroll
  for (int i = 0; i < 4; ++i)
    t[ty + i * 8][tx] = src[(size_t)(k0 + ty + i * 8) * Ncols + (c0 + tx)];
  __syncthreads();
#pragma unroll
  for (int i = 0; i < 4; ++i)
    out[(size_t)(n0 + ty + i * 8) * K + (k0 + tx)] = f2bf(t[tx][ty + i * 8]);
}

// ---------------- RMSNorm (f32 in, bf16 out), one block per row, D=1024
__global__ __launch_bounds__(256) void rmsnorm_kernel(const float* __restrict__ x,
                                                      const float* __restrict__ g,
                                                      u16* __restrict__ out) {
  const int row = blockIdx.x;
  const int t = threadIdx.x;
  const float4 v = ((const float4*)(x + (size_t)row * kD))[t];
  float ss = v.x * v.x + v.y * v.y + v.z * v.z + v.w * v.w;
#pragma unroll
  for (int o = 1; o < 64; o <<= 1) ss += __shfl_xor(ss, o, 64);
  __shared__ float red[4];
  if ((t & 63) == 0) red[t >> 6] = ss;
  __syncthreads();
  const float tot = red[0] + red[1] + red[2] + red[3];
  const float sc = rsqrtf(tot * (1.0f / kD) + kEPS);
  const float4 gv = ((const float4*)g)[t];
  const uint32_t lo = (uint32_t)f2bf(v.x * sc * gv.x) | ((uint32_t)f2bf(v.y * sc * gv.y) << 16);
  const uint32_t hi = (uint32_t)f2bf(v.z * sc * gv.z) | ((uint32_t)f2bf(v.w * sc * gv.w) << 16);
  *(uint2*)(out + (size_t)row * kD + t * 4) = make_uint2(lo, hi);
}

// ---------------- 256x256 lockstep 4-phase GEMM, deep in-place ring staging.
// 512 thr = 8 waves (2M x 4N), BK=64, 128 KiB LDS (2 slots), T2 XOR swizzle via
// pre-swizzled global source, T1 XCD swizzle, T5 setprio.
// Region liveness (slot h&1): A halves (#0,#1) last read ph3 (ah); B halves
// (#2,#3) last read ph2 (bh). Reads are certified by each wave's lgkmcnt(0)
// before that phase's MFMA, so the end-of-phase barrier certifies the region.
// In-place ring staging of tile h+2 into slot h&1:
//   ph3(h): stage B-lo,B-hi(h+2)   [after ph2-end barrier]  4 gloads
//   ph4(h): stage A-lo,A-hi(h+2)   [after ph3-end barrier]  4 gloads
// Per-wave queue = 8 loads/iter -> vmcnt(8) at ph4-end certifies tile h+1
// (vmcnt completes in order), giving every load 4-5 phases of flight time.
// Tail: vmcnt(0) when h+2>=NK. No cross-phase register pipelining (lockstep).
// MODE 2: Cf = v*silu(aux) + res        (y + residual; aux bf16)
// MODE 4: Cf = v + res                  (final out)
// MODE 5: Cb = bf16(v)                  (raw bf16)
// MODE 6: pair FFN: v1=fca(gate), v2=fc -> Cb = bf16(v2*silu(v1)), Nout=N/2
// MODE 7: pair coeffs: v1=z, v2=dt -> Cf = sigm(-v2), C2 = sigm(v1)*sigm(v2), Nout=N/2
template <int MODE>
__global__ __launch_bounds__(512) void gemm256(
    const u16* __restrict__ A, const u16* __restrict__ Bt,
    const float* __restrict__ bias, const float* __restrict__ bias2,
    const u16* __restrict__ aux, int auxld,
    const float* __restrict__ res, float* __restrict__ Cf,
    u16* __restrict__ Cb, float* __restrict__ C2,
    int M, int N, int K) {
  __shared__ u16 sm[65536];  // 128 KiB
  const int tid = threadIdx.x;
  const int lane = tid & 63;
  const int wave = tid >> 6;
  const int wr = wave >> 2, wc = wave & 3;  // 2 x 4 wave grid

  // bijective XCD swizzle (m204)
  const int gx = gridDim.x;
  const int nwg = gx * gridDim.y;
  const int bid = blockIdx.y * gx + blockIdx.x;
  const int q = nwg >> 3, r = nwg & 7;
  const int xcd = bid & 7, idx0 = bid >> 3;
  const int wg = (xcd < r ? xcd * (q + 1) : r * (q + 1) + (xcd - r) * q) + idx0;
  const int m0 = (wg / gx) * 256, n0 = (wg % gx) * 256;

  const int NK = K >> 6;

  // staging: linear LDS dest, inverse-swizzled global source.
  const int l8 = lane >> 3, l7 = lane & 7;
  const int rsub = wave * 8 + l8;
  const int kel = (l7 ^ l8) * 8;
  const size_t srcA = (size_t)(m0 + rsub) * K + kel;
  const size_t srcB = (size_t)(n0 + rsub) * K + kel;

  // half: 0 = A rows 0-127, 1 = A rows 128-255, 2 = B rows 0-127, 3 = B rows 128-255
  auto stage_half = [&](int kt, int half) {
    const int bsel = (kt & 1) * 32768;
    if (half < 2) {
      u16* d = sm + bsel + tid * 8 + half * 8192;
      const u16* s = A + srcA + (size_t)kt * 64 + (size_t)(half * 2) * 64 * K;
      gload_lds16(s, d);
      gload_lds16(s + (size_t)64 * K, d + 4096);
    } else {
      const int hh = half - 2;
      u16* d = sm + bsel + 16384 + tid * 8 + hh * 8192;
      const u16* s = Bt + srcB + (size_t)kt * 64 + (size_t)(hh * 2) * 64 * K;
      gload_lds16(s, d);
      gload_lds16(s + (size_t)64 * K, d + 4096);
    }
  };

  // fragment-read offsets (swizzled)
  const int ra = lane & 15;
  const int kx0 = ((lane >> 4) ^ l7) * 8;
  const int kx1 = (((lane >> 4) + 4) ^ l7) * 8;

  f32x4 acc[8][4] = {};
  bf16x8 al[4][2], ah[4][2], bl[2][2], bh[2][2];

  // prologue: tiles 0 and 1 fully staged; vmcnt(8) -> tile0 landed (tile1 in flight)
  stage_half(0, 0); stage_half(0, 1); stage_half(0, 2); stage_half(0, 3);
  if (NK > 1) { stage_half(1, 0); stage_half(1, 1); stage_half(1, 2); stage_half(1, 3); }
  asm volatile("s_waitcnt vmcnt(8)");
  asm volatile("s_barrier" ::: "memory");

  for (int h = 0; h < NK; ++h) {
    const u16* Az = sm + (h & 1) * 32768 + (wr * 128 + ra) * 64;
    const u16* Bz = sm + (h & 1) * 32768 + 16384 + (wc * 64 + ra) * 64;

    // ---- Phase 1: read A-lo + B-lo; MFMA lo x lo
#pragma unroll
    for (int mi = 0; mi < 4; ++mi) {
      al[mi][0] = *(const bf16x8*)(Az + mi * 16 * 64 + kx0);
      al[mi][1] = *(const bf16x8*)(Az + mi * 16 * 64 + kx1);
    }
#pragma unroll
    for (int ni = 0; ni < 2; ++ni) {
      bl[ni][0] = *(const bf16x8*)(Bz + ni * 16 * 64 + kx0);
      bl[ni][1] = *(const bf16x8*)(Bz + ni * 16 * 64 + kx1);
    }
    asm volatile("s_barrier" ::: "memory");
    asm volatile("s_waitcnt lgkmcnt(0)");
    __builtin_amdgcn_s_setprio(1);
#pragma unroll
    for (int mi = 0; mi < 4; ++mi)
#pragma unroll
      for (int ni = 0; ni < 2; ++ni)
#pragma unroll
        for (int kk = 0; kk < 2; ++kk)
          acc[mi][ni] = __builtin_amdgcn_mfma_f32_16x16x32_bf16(al[mi][kk], bl[ni][kk], acc[mi][ni], 0, 0, 0);
    __builtin_amdgcn_s_setprio(0);
    asm volatile("s_barrier" ::: "memory");

    // ---- Phase 2: read B-hi; MFMA lo x hi
#pragma unroll
    for (int ni = 0; ni < 2; ++ni) {
      bh[ni][0] = *(const bf16x8*)(Bz + (32 + ni * 16) * 64 + kx0);
      bh[ni][1] = *(const bf16x8*)(Bz + (32 + ni * 16) * 64 + kx1);
    }
    asm volatile("s_barrier" ::: "memory");
    asm volatile("s_waitcnt lgkmcnt(0)");
    __builtin_amdgcn_s_setprio(1);
#pragma unroll
    for (int mi = 0; mi < 4; ++mi)
#pragma unroll
      for (int ni = 0; ni < 2; ++ni)
#pragma unroll
        for (int kk = 0; kk < 2; ++kk)
          acc[mi][2 + ni] = __builtin_amdgcn_mfma_f32_16x16x32_bf16(al[mi][kk], bh[ni][kk], acc[mi][2 + ni], 0, 0, 0);
    __builtin_amdgcn_s_setprio(0);
    asm volatile("s_barrier" ::: "memory");

    // ---- Phase 3: read A-hi; stage B(h+2) into B regions (certified dead at ph2-end);
    //      MFMA hi x lo
#pragma unroll
    for (int mi = 0; mi < 4; ++mi) {
      ah[mi][0] = *(const bf16x8*)(Az + (64 + mi * 16) * 64 + kx0);
      ah[mi][1] = *(const bf16x8*)(Az + (64 + mi * 16) * 64 + kx1);
    }
    if (h + 2 < NK) { stage_half(h + 2, 2); stage_half(h + 2, 3); }
    asm volatile("s_barrier" ::: "memory");
    asm volatile("s_waitcnt lgkmcnt(0)");
    __builtin_amdgcn_s_setprio(1);
#pragma unroll
    for (int mi = 0; mi < 4; ++mi)
#pragma unroll
      for (int ni = 0; ni < 2; ++ni)
#pragma unroll
        for (int kk = 0; kk < 2; ++kk)
          acc[4 + mi][ni] = __builtin_amdgcn_mfma_f32_16x16x32_bf16(ah[mi][kk], bl[ni][kk], acc[4 + mi][ni], 0, 0, 0);
    __builtin_amdgcn_s_setprio(0);
    asm volatile("s_barrier" ::: "memory");

    // ---- Phase 4: stage A(h+2) into A regions (certified dead at ph3-end);
    //      MFMA hi x hi (regs only); counted vmcnt certifies tile h+1; barrier
    if (h + 2 < NK) { stage_half(h + 2, 0); stage_half(h + 2, 1); }
    __builtin_amdgcn_s_setprio(1);
#pragma unroll
    for (int mi = 0; mi < 4; ++mi)
#pragma unroll
      for (int ni = 0; ni < 2; ++ni)
#pragma unroll
        for (int kk = 0; kk < 2; ++kk)
          acc[4 + mi][2 + ni] = __builtin_amdgcn_mfma_f32_16x16x32_bf16(ah[mi][kk], bh[ni][kk], acc[4 + mi][2 + ni], 0, 0, 0);
    __builtin_amdgcn_s_setprio(0);
    if (h + 2 < NK) asm volatile("s_waitcnt vmcnt(8)");  // oldest 8 (= tile h+1) landed
    else            asm volatile("s_waitcnt vmcnt(0)");  // tail: full drain
    asm volatile("s_barrier" ::: "memory");
  }

  // ---- epilogue. C/D layout: col = lane&15, row = (lane>>4)*4 + j
  const int ca = ra;
  const int rq = (lane >> 4) * 4;
  if (MODE == 6 || MODE == 7) {
    const int Nout = N >> 1;
#pragma unroll
    for (int mi = 0; mi < 8; ++mi) {
#pragma unroll
      for (int ni = 0; ni < 2; ++ni) {
        const int cout = (n0 >> 1) + wc * 32 + ni * 16 + ca;
        const float b1 = bias[cout], b2 = bias2[cout];
#pragma unroll
        for (int j = 0; j < 4; ++j) {
          const int rr = m0 + wr * 128 + mi * 16 + rq + j;
          const size_t idx = (size_t)rr * Nout + cout;
          const float v1 = acc[mi][ni][j] + b1;
          const float v2 = acc[mi][2 + ni][j] + b2;
          if (MODE == 7) {
            Cf[idx] = sigm(-v2);              // decay A
            C2[idx] = sigm(v1) * sigm(v2);    // input B
          } else {
            Cb[idx] = f2bf(v2 * (v1 * sigm(v1)));  // fc * silu(fca)
          }
        }
      }
    }
  } else {
#pragma unroll
    for (int mi = 0; mi < 8; ++mi) {
#pragma unroll
      for (int ni = 0; ni < 4; ++ni) {
        const int c = n0 + wc * 64 + ni * 16 + ca;
        const float bz = bias[c];
#pragma unroll
        for (int j = 0; j < 4; ++j) {
          const int rr = m0 + wr * 128 + mi * 16 + rq + j;
          const size_t idx = (size_t)rr * N + c;
          const float v = acc[mi][ni][j] + bz;
          if (MODE == 2) {
            const float a = bf2f(aux[(size_t)rr * auxld + c]);
            Cf[idx] = v * (a * sigm(a)) + res[idx];
          } else if (MODE == 4) {
            Cf[idx] = v + res[idx];
          } else {  // MODE 5
            Cb[idx] = f2bf(v);
          }
        }
      }
    }
  }
}

// ---------------- chunked scan: h[l] = A[l]*h[l-1] + B[l]
__global__ __launch_bounds__(256) void scan_phase1(const float* __restrict__ Aa,
                                                   const float* __restrict__ Bv,
                                                   float* __restrict__ P,
                                                   float* __restrict__ S) {
  const int d = blockIdx.x * 256 + threadIdx.x;
  const int c = blockIdx.y, b = blockIdx.z;
  size_t base = ((size_t)b * kL + (size_t)c * kLC) * kD + d;
  float p = 1.0f, s = 0.0f;
#pragma unroll 4
  for (int l = 0; l < kLC; ++l) {
    const float a = Aa[base];
    const float bv = Bv[base];
    p *= a;
    s = fmaf(a, s, bv);
    base += kD;
  }
  const size_t o = ((size_t)b * kNC + c) * kD + d;
  P[o] = p; S[o] = s;
}

__global__ __launch_bounds__(256) void scan_phase2(const float* __restrict__ P,
                                                   const float* __restrict__ S,
                                                   const float* __restrict__ hidden,
                                                   float* __restrict__ Hini) {
  const int d = blockIdx.x * 256 + threadIdx.x;
  const int b = blockIdx.y;
  float carry = hidden[(size_t)b * kD + d];
  for (int c = 0; c < kNC; ++c) {
    const size_t o = ((size_t)b * kNC + c) * kD + d;
    Hini[o] = carry;
    carry = fmaf(P[o], carry, S[o]);
  }
}

__global__ __launch_bounds__(256) void scan_phase3(const float* __restrict__ Aa,
                                                   const float* __restrict__ Bv,
                                                   const float* __restrict__ Hini,
                                                   float* __restrict__ Hout,
                                                   u16* __restrict__ Hbf) {
  const int d = blockIdx.x * 256 + threadIdx.x;
  const int c = blockIdx.y, b = blockIdx.z;
  float h = Hini[((size_t)b * kNC + c) * kD + d];
  size_t base = ((size_t)b * kL + (size_t)c * kLC) * kD + d;
#pragma unroll 4
  for (int l = 0; l < kLC; ++l) {
    h = fmaf(Aa[base], h, Bv[base]);
    Hout[base] = h;
    Hbf[base] = f2bf(h);
    base += kD;
  }
}

// ---------------- host
extern "C" void kernel_launch(void* const* d_in, const int* in_sizes, int n_in,
                              void* d_out, int out_size, void* d_ws, size_t ws_size,
                              hipStream_t stream) {
  const float* x      = (const float*)d_in[0];
  const float* hidden = (const float*)d_in[1];
  const float* w_ln_z = (const float*)d_in[2];
  const float* b_ln_z = (const float*)d_in[3];
  const float* w_dt   = (const float*)d_in[4];
  const float* b_dt   = (const float*)d_in[5];
  const float* w_y    = (const float*)d_in[6];
  const float* b_y    = (const float*)d_in[7];
  const float* w_yact = (const float*)d_in[8];
  const float* b_yact = (const float*)d_in[9];
  const float* w_fc   = (const float*)d_in[10];
  const float* b_fc   = (const float*)d_in[11];
  const float* w_fca  = (const float*)d_in[12];
  const float* b_fca  = (const float*)d_in[13];
  const float* w_out  = (const float*)d_in[14];
  const float* b_out  = (const float*)d_in[15];
  const float* g_sio  = (const float*)d_in[16];
  const float* g_ffn  = (const float*)d_in[17];

  char* ws = (char*)d_ws;
  const size_t MiB = 1ull << 20;
  u16* wzdT  = (u16*)(ws + 0 * MiB);      // [2048,1024] paired z|dt, 4 MiB
  u16* wyaT  = (u16*)(ws + 4 * MiB);      // 2 MiB
  u16* wyT   = (u16*)(ws + 6 * MiB);      // 2 MiB
  u16* wfgT  = (u16*)(ws + 8 * MiB);      // [8192,1024] paired fca|fc, 16 MiB
  u16* woutT = (u16*)(ws + 24 * MiB);     // [1024,4096] 8 MiB
  u16*   xn    = (u16*)(ws + 33 * MiB);   // [M,D] bf16 32 MiB (reused as xn2)
  u16*   yabuf = (u16*)(ws + 65 * MiB);   // [M,D] bf16 32 MiB
  float* Abuf  = (float*)(ws + 97 * MiB); // [M,D] f32 64 MiB (reused as x1)
  float* Bvbuf = (float*)(ws + 161 * MiB);// [M,D] f32 64 MiB (dead after scan)
  u16*   hbf   = (u16*)(ws + 225 * MiB);  // [M,D] bf16 32 MiB (dead after y-GEMM)
  u16*   Ubuf  = (u16*)(ws + 161 * MiB);  // [M,FF] bf16 128 MiB, overlays dead Bv/hbf; ends 289
  float* Pbuf  = (float*)(ws + 289 * MiB);
  float* Sbuf  = (float*)(ws + 290 * MiB);
  float* Hini  = (float*)(ws + 291 * MiB);// ends 292 MiB

  float* xout = (float*)d_out;
  float* hout = xout + (size_t)kM * kD;
  float* x1 = Abuf;

  const dim3 tb(32, 8);
  wtrans_pair<<<dim3(2048 / 32, kD / 32), tb, 0, stream>>>(w_ln_z, w_dt, wzdT, kD, kD);
  wtrans_pair<<<dim3(8192 / 32, kD / 32), tb, 0, stream>>>(w_fca, w_fc, wfgT, kD, kFF);
  wtrans_kernel<<<dim3(kD / 32, kD / 32), tb, 0, stream>>>(w_yact, wyaT, kD, kD);
  wtrans_kernel<<<dim3(kD / 32, kD / 32), tb, 0, stream>>>(w_y, wyT, kD, kD);
  wtrans_kernel<<<dim3(kD / 32, kFF / 32), tb, 0, stream>>>(w_out, woutT, kFF, kD);

  rmsnorm_kernel<<<kM, 256, 0, stream>>>(x, g_sio, xn);

  // paired z|dt GEMM -> A = sigm(-dt), Bv = sigm(z)*sigm(dt)   (no z materialized)
  gemm256<7><<<dim3(2048 / 256, kM / 256), 512, 0, stream>>>(
      xn, wzdT, b_ln_z, b_dt, nullptr, 0, nullptr, Abuf, nullptr, Bvbuf, kM, 2048, kD);
  // ya = xn @ w_y_act + b (bf16)
  gemm256<5><<<dim3(kD / 256, kM / 256), 512, 0, stream>>>(
      xn, wyaT, b_yact, nullptr, nullptr, 0, nullptr, nullptr, yabuf, nullptr, kM, kD, kD);

  scan_phase1<<<dim3(kD / 256, kNC, kB), 256, 0, stream>>>(Abuf, Bvbuf, Pbuf, Sbuf);
  scan_phase2<<<dim3(kD / 256, kB), 256, 0, stream>>>(Pbuf, Sbuf, hidden, Hini);
  scan_phase3<<<dim3(kD / 256, kNC, kB), 256, 0, stream>>>(Abuf, Bvbuf, Hini, hout, hbf);

  // x1 = (h @ w_y + b_y) * silu(ya) + x   (x1 reuses Abuf; A/Bv dead after scan)
  gemm256<2><<<dim3(kD / 256, kM / 256), 512, 0, stream>>>(
      hbf, wyT, b_y, nullptr, yabuf, kD, x, x1, nullptr, nullptr, kM, kD, kD);

  rmsnorm_kernel<<<kM, 256, 0, stream>>>(x1, g_ffn, xn);

  // paired FFN up+gate: U = fc * silu(fca), full M, in-register gating
  gemm256<6><<<dim3(8192 / 256, kM / 256), 512, 0, stream>>>(
      xn, wfgT, b_fca, b_fc, nullptr, 0, nullptr, nullptr, Ubuf, nullptr, kM, 8192, kD);

  // xout = U @ w_out + b_out + x1  (K=4096)
  gemm256<4><<<dim3(kD / 256, kM / 256), 512, 0, stream>>>(
      Ubuf, woutT, b_out, nullptr, nullptr, 0, x1, xout, nullptr, nullptr, kM, kD, kFF);
}